// Round 21
// baseline (38.578 us; speedup 1.0000x reference)
//
#include <hip/hip_runtime.h>
#include <hip/hip_bf16.h>
#include <math.h>

typedef short short8 __attribute__((ext_vector_type(8)));
typedef float f32x4 __attribute__((ext_vector_type(4)));

#define NQ 32
#define NDOCS 8
#define QLEN 32
#define DLEN 200
#define DIM 128
#define MD 256            // total docs
#define ROWB 256          // LDS row stride bytes (128 bf16)

// HW bf16 convert (v_cvt_pk_bf16_f32 via compiler; RNE, same numerics as before)
__device__ __forceinline__ short8 cvt8(float4 f0, float4 f1) {
    union { __hip_bfloat16 h[8]; short8 s; } u;
    u.h[0] = __float2bfloat16(f0.x); u.h[1] = __float2bfloat16(f0.y);
    u.h[2] = __float2bfloat16(f0.z); u.h[3] = __float2bfloat16(f0.w);
    u.h[4] = __float2bfloat16(f1.x); u.h[5] = __float2bfloat16(f1.y);
    u.h[6] = __float2bfloat16(f1.z); u.h[7] = __float2bfloat16(f1.w);
    return u.s;
}

// local chunk c (8 bf16) within a 32-row buffer: row=c>>4 (0..31), kc=c&15;
// XOR-swizzled write — same formula as R15 (row&7 preserved: buffers tile-aligned).
__device__ __forceinline__ void writeChunk(char* buf, int c, float4 f0, float4 f1) {
    int row = c >> 4, kc = c & 15;
    int byte = row * ROWB + ((kc * 16) ^ ((row & 7) << 4));
    *reinterpret_cast<short8*>(&buf[byte]) = cvt8(f0, f1);
}

// R15 math + T3 minimum-2-phase double-buffered pipeline.
// grid = 1024: b = qo*256 + m (b%8 = m%8 -> all 4 blocks of doc m on one XCD).
// Block: 256 thr / 4 waves; wave wid: questions n = qo*8 + wid*2 + {0,1} (Q=2).
// LDS = 2 x 8KB buffers (2 tiles each). Iteration g: prefetch group g+1 (regs),
// compute tiles {2g,2g+1} from buf[g&1], write g+1 -> buf[(g+1)&1], barrier.
// 13 tiles = 6 full groups + 1-tile tail (group 6, masked).
// C = mfma(A=hd_frag, B=hq_frag): lane holds C[d = dt*16 + lg*4 + r][q = qt*16 + lr].
__global__ __launch_bounds__(256, 2) void colbert_scores(const float* __restrict__ hq,
                                                         const float* __restrict__ hd,
                                                         float* __restrict__ out) {
    __shared__ char lds[2][32 * ROWB];   // 2 x 8192 B
    const int tid = threadIdx.x;
    const int b = blockIdx.x;
    const int m = b & 255, qo = b >> 8;
    const int wid = tid >> 6, lane = tid & 63;
    const int lg = lane >> 4, lr = lane & 15;
    const int n0 = qo * 8 + wid * 2;

    const float4* src4 = reinterpret_cast<const float4*>(hd + (size_t)m * (DLEN * DIM));

    // ---- Bq for 2 questions (hq fp32 -> bf16, HW cvt): 64 VGPR held ----
    short8 Bq[2][2][4];
    #pragma unroll
    for (int nn = 0; nn < 2; ++nn)
        #pragma unroll
        for (int qt = 0; qt < 2; ++qt)
            #pragma unroll
            for (int s = 0; s < 4; ++s) {
                const float4* p = reinterpret_cast<const float4*>(
                    hq + (size_t)((n0 + nn) * QLEN + qt * 16 + lr) * DIM + s * 32 + lg * 8);
                Bq[nn][qt][s] = cvt8(p[0], p[1]);
            }

    // ---- prologue: stage group 0 (tiles 0,1 = chunks 0..511) into buf0 ----
    {
        float4 a0 = src4[tid * 2],           a1 = src4[tid * 2 + 1];
        float4 b0 = src4[(tid + 256) * 2],   b1 = src4[(tid + 256) * 2 + 1];
        writeChunk(lds[0], tid, a0, a1);
        writeChunk(lds[0], tid + 256, b0, b1);
    }
    __syncthreads();

    int va[4];
    #pragma unroll
    for (int s = 0; s < 4; ++s)
        va[s] = lr * ROWB + ((s * 64 + lg * 16) ^ ((lr & 7) << 4));

    float qmax[2][2];
    #pragma unroll
    for (int nn = 0; nn < 2; ++nn)
        #pragma unroll
        for (int qt = 0; qt < 2; ++qt) qmax[nn][qt] = -INFINITY;

#define STEP(BUF, TL, MASKED)                                                     \
    {                                                                             \
        f32x4 a00 = {0,0,0,0}, a01 = {0,0,0,0}, a10 = {0,0,0,0}, a11 = {0,0,0,0}; \
        _Pragma("unroll")                                                         \
        for (int s = 0; s < 4; ++s) {                                             \
            short8 A_ = *reinterpret_cast<const short8*>(&(BUF)[va[s] + (TL) * 4096]); \
            a00 = __builtin_amdgcn_mfma_f32_16x16x32_bf16(A_, Bq[0][0][s], a00, 0, 0, 0); \
            a01 = __builtin_amdgcn_mfma_f32_16x16x32_bf16(A_, Bq[0][1][s], a01, 0, 0, 0); \
            a10 = __builtin_amdgcn_mfma_f32_16x16x32_bf16(A_, Bq[1][0][s], a10, 0, 0, 0); \
            a11 = __builtin_amdgcn_mfma_f32_16x16x32_bf16(A_, Bq[1][1][s], a11, 0, 0, 0); \
        }                                                                         \
        if (!(MASKED) || lg < 2) {                                                \
            qmax[0][0] = fmaxf(qmax[0][0], fmaxf(fmaxf(a00[0], a00[1]), fmaxf(a00[2], a00[3]))); \
            qmax[0][1] = fmaxf(qmax[0][1], fmaxf(fmaxf(a01[0], a01[1]), fmaxf(a01[2], a01[3]))); \
            qmax[1][0] = fmaxf(qmax[1][0], fmaxf(fmaxf(a10[0], a10[1]), fmaxf(a10[2], a10[3]))); \
            qmax[1][1] = fmaxf(qmax[1][1], fmaxf(fmaxf(a11[0], a11[1]), fmaxf(a11[2], a11[3]))); \
        }                                                                         \
    }

    // ---- pipeline: g = 0..4 (full prefetch of g+1), g = 5 (tail prefetch) ----
    #pragma unroll 1
    for (int g = 0; g < 5; ++g) {
        const int base = (g + 1) * 512;
        float4 a0 = src4[(base + tid) * 2],        a1 = src4[(base + tid) * 2 + 1];
        float4 b0 = src4[(base + tid + 256) * 2],  b1 = src4[(base + tid + 256) * 2 + 1];
        char* cur = lds[g & 1];
        STEP(cur, 0, false);
        STEP(cur, 1, false);
        char* nxt = lds[(g + 1) & 1];
        writeChunk(nxt, tid, a0, a1);
        writeChunk(nxt, tid + 256, b0, b1);
        __syncthreads();
    }
    {   // g = 5: prefetch tail group 6 (tile 12: 128 real chunks + zeros)
        float4 a0 = {0,0,0,0}, a1 = {0,0,0,0};
        if (tid < 128) { a0 = src4[(3072 + tid) * 2]; a1 = src4[(3072 + tid) * 2 + 1]; }
        STEP(lds[1], 0, false);   // tile 10
        STEP(lds[1], 1, false);   // tile 11
        writeChunk(lds[0], tid, a0, a1);
        __syncthreads();
    }
    STEP(lds[0], 0, true);        // tile 12: rows 192..199 valid only for lg<2
#undef STEP

    // max over d: combine the 4 lg groups (lanes ^16, ^32)
    #pragma unroll
    for (int off = 16; off <= 32; off <<= 1)
        #pragma unroll
        for (int nn = 0; nn < 2; ++nn)
            #pragma unroll
            for (int qt = 0; qt < 2; ++qt)
                qmax[nn][qt] = fmaxf(qmax[nn][qt], __shfl_xor(qmax[nn][qt], off, 64));

    // mean over q-tokens: lane lr holds tokens lr and 16+lr; sum across the 16 lr lanes
    float s0 = qmax[0][0] + qmax[0][1];
    float s1 = qmax[1][0] + qmax[1][1];
    #pragma unroll
    for (int off = 1; off <= 8; off <<= 1) {
        s0 += __shfl_xor(s0, off, 64);
        s1 += __shfl_xor(s1, off, 64);
    }
    if (lane == 0) {
        out[(size_t)n0 * MD + m] = s0 * (1.0f / 32.0f);
        out[(size_t)(n0 + 1) * MD + m] = s1 * (1.0f / 32.0f);
    }
}

// loss = mean_n( logsumexp(row_n) - row_n[8n] )
__global__ __launch_bounds__(256) void colbert_loss(const float* __restrict__ scores,
                                                    float* __restrict__ loss_out) {
    __shared__ float terms[NQ];
    const int tid = threadIdx.x;
    const int wid = tid >> 6, lane = tid & 63;
    for (int n = wid; n < NQ; n += 4) {
        const float* row = scores + n * MD;
        float v0 = row[lane], v1 = row[64 + lane], v2 = row[128 + lane], v3 = row[192 + lane];
        float mx = fmaxf(fmaxf(v0, v1), fmaxf(v2, v3));
        #pragma unroll
        for (int off = 1; off < 64; off <<= 1) mx = fmaxf(mx, __shfl_xor(mx, off, 64));
        float s = expf(v0 - mx) + expf(v1 - mx) + expf(v2 - mx) + expf(v3 - mx);
        #pragma unroll
        for (int off = 1; off < 64; off <<= 1) s += __shfl_xor(s, off, 64);
        if (lane == 0) terms[n] = (mx + logf(s)) - row[n * NDOCS];
    }
    __syncthreads();
    if (tid == 0) {
        float acc = 0.f;
        #pragma unroll
        for (int n = 0; n < NQ; ++n) acc += terms[n];
        loss_out[0] = acc * (1.0f / NQ);
    }
}

extern "C" void kernel_launch(void* const* d_in, const int* in_sizes, int n_in,
                              void* d_out, int out_size, void* d_ws, size_t ws_size,
                              hipStream_t stream) {
    const float* hq = (const float*)d_in[0];   // [32][32][128] f32
    const float* hd = (const float*)d_in[1];   // [256][200][128] f32
    float* out = (float*)d_out;                // 8192 scores + 1 loss

    colbert_scores<<<1024, 256, 0, stream>>>(hq, hd, out);
    colbert_loss<<<1, 256, 0, stream>>>(out, out + NQ * MD);
}